// Round 20
// baseline (48.664 us; speedup 1.0000x reference)
//
#include <hip/hip_runtime.h>

// 8 lanes per batch element; 2 hidden units per lane packed as float2.
// Parallel chunk evaluation (R19): refresh -> quadratic Taylor p(tau) at each
// lane's 2 own steps -> weighted prefix scan for outputs.
// R20: the carried-state cycle (CRv, tprev) is cut to its minimum --
// chunk totals via DPP butterfly red8 (VALU) instead of ds_swizzle (LDS),
// tprev advanced by the telescoped h-sum, and the carried update hoisted
// BEFORE the scan/stores so they fall off the cross-chunk critical path.
#define LPE 8
#define CH 16   // steps per chunk == refresh period

typedef float v2f __attribute__((ext_vector_type(2)));

#if __has_builtin(__builtin_amdgcn_exp2f)
  #define EXP2F(x) __builtin_amdgcn_exp2f(x)
#else
  #define EXP2F(x) exp2f(x)
#endif
#if __has_builtin(__builtin_amdgcn_rcpf)
  #define RCPF(x) __builtin_amdgcn_rcpf(x)
#else
  #define RCPF(x) (1.0f/(x))
#endif

template<int CTRL>
__device__ __forceinline__ float dpp_add(float x) {
    int y = __builtin_amdgcn_update_dpp(0, __float_as_int(x), CTRL, 0xF, 0xF, true);
    return x + __int_as_float(y);
}
// butterfly sum over aligned 8-lane groups; all lanes get the total
__device__ __forceinline__ float red8(float v) {
    v = dpp_add<0xB1>(v);
    v = dpp_add<0x4E>(v);
    v = dpp_add<0x141>(v);
    return v;
}
// dpp row_shr:K with bound_ctrl (OOB -> 0)
template<int CTRL>
__device__ __forceinline__ float dpp_shr(float x) {
    int y = __builtin_amdgcn_update_dpp(0, __float_as_int(x), CTRL, 0xF, 0xF, true);
    return __int_as_float(y);
}

__device__ __forceinline__ v2f vfma(v2f a, v2f b, v2f c) {
#if __has_builtin(__builtin_elementwise_fma)
    return __builtin_elementwise_fma(a, b, c);
#else
    v2f r; r.x = fmaf(a.x, b.x, c.x); r.y = fmaf(a.y, b.y, c.y); return r;
#endif
}
__device__ __forceinline__ v2f splat(float x) { v2f v; v.x = x; v.y = x; return v; }

#define MEMBAR() __asm__ __volatile__("" ::: "memory")

__global__ __launch_bounds__(256, 1) void ode_scan(
    const float* __restrict__ t,
    const float* __restrict__ Vs,
    const float* __restrict__ Tm,
    const float* __restrict__ C0,
    const float* __restrict__ R0,
    const float* __restrict__ W1,   // (5,10)
    const float* __restrict__ b1,   // (10)
    const float* __restrict__ W2,   // (10,5)
    const float* __restrict__ b2,   // (5)
    float* __restrict__ out,        // (B, N+1, 2)
    int B, int N)
{
    int tid = blockIdx.x * blockDim.x + threadIdx.x;
    int e = tid >> 3;
    int u = tid & 7;
    if (e >= B) return;

    const float S   = 2.88539008177792681472f;   // 2*log2(e)
    const float LN2 = 0.69314718055994530942f;
    float Vv = Vs[e], Tv = Tm[e];

    // Packed per-lane weights for hidden units j0=2u (x), j1=2u+1 (y).
    v2f W0p, W3p, W4p, CCp, V3p, V4p;
    {
        int j0 = 2*u, j1 = 2*u + 1;
        if (j0 < 10) {
            W0p.x = S*W1[j0]; W3p.x = S*W1[30+j0]; W4p.x = S*W1[40+j0];
            CCp.x = S*fmaf(Vv, W1[10+j0], fmaf(Tv, W1[20+j0], b1[j0]));
            V3p.x = -2.0f*W2[5*j0+3]; V4p.x = -2.0f*W2[5*j0+4];
        } else { W0p.x=0.f; W3p.x=0.f; W4p.x=0.f; CCp.x=-60.f; V3p.x=0.f; V4p.x=0.f; }
        if (j1 < 10) {
            W0p.y = S*W1[j1]; W3p.y = S*W1[30+j1]; W4p.y = S*W1[40+j1];
            CCp.y = S*fmaf(Vv, W1[10+j1], fmaf(Tv, W1[20+j1], b1[j1]));
            V3p.y = -2.0f*W2[5*j1+3]; V4p.y = -2.0f*W2[5*j1+4];
        } else { W0p.y=0.f; W3p.y=0.f; W4p.y=0.f; CCp.y=-60.f; V3p.y=0.f; V4p.y=0.f; }
        if (j0 == 10) {
            // constant unit: a=-60 -> r==1.0 exactly, s==0 -> contributes the
            // exact constant to p3,p4 at refresh and ZERO to all C's.
            float c3 = b2[3], c4 = b2[4];
            for (int j = 0; j < 10; ++j) { c3 += W2[5*j+3]; c4 += W2[5*j+4]; }
            V3p.x = c3; V4p.x = c4;
        }
    }

    const v2f ONEv = splat(1.0f);
    v2f W0a = splat(LN2) * W0p, W3a = splat(LN2) * W3p, W4a = splat(LN2) * W4p;
    v2f M30 = W0a * V3p, M33 = W3a * V3p, M34 = W4a * V3p;
    v2f M40 = W0a * V4p, M43 = W3a * V4p, M44 = W4a * V4p;

    const float* trow = t + (size_t)e * (N + 1);
    float* orow = out + (size_t)e * (size_t)(N + 1) * 2;
    v2f CRv;                      // (Cap, Res) packed, group-uniform
    CRv.x = C0[e]; CRv.y = R0[e];
    *(float2*)orow = make_float2(CRv.x, CRv.y);
    float tprev = trow[0];        // group-uniform chunk-start t

    // group-uniform packed state
    v2f pv  = splat(0.0f);                      // (p3, p4)
    v2f C0v = splat(0.0f), C3v = splat(0.0f), C4v = splat(0.0f);

    // refresh: exact per-unit r from (tprev, CRv), reduce p0 and the six C's.
    auto refresh = [&]() {
        v2f TP = vfma(splat(tprev), W0p, CCp);
        v2f A  = vfma(splat(CRv.y), W4p, vfma(splat(CRv.x), W3p, TP));
        v2f zz; zz.x = EXP2F(A.x); zz.y = EXP2F(A.y);
        v2f dd = zz + ONEv;
        v2f rr; rr.x = RCPF(dd.x); rr.y = RCPF(dd.y);
        v2f ss = vfma(rr, rr, -rr);      // s = r^2 - r
        v2f l3 = rr * V3p, l4 = rr * V4p;
        v2f k30 = ss * M30, k33 = ss * M33, k34 = ss * M34;
        v2f k40 = ss * M40, k43 = ss * M43, k44 = ss * M44;
        pv.x  = red8(l3.x + l3.y);
        pv.y  = red8(l4.x + l4.y);
        C0v.x = red8(k30.x + k30.y);
        C3v.x = red8(k33.x + k33.y);
        C4v.x = red8(k34.x + k34.y);
        C0v.y = red8(k40.x + k40.y);
        C3v.y = red8(k43.x + k43.y);
        C4v.y = red8(k44.x + k44.y);
    };

    // sequential exact step (tail only)
    auto fstep = [&](float tn) {
        float h  = tn - tprev;
        v2f hv   = splat(h);
        v2f uv   = vfma(splat(pv.y), C4v, vfma(splat(pv.x), C3v, C0v));
        CRv = vfma(hv, pv, CRv);
        pv  = vfma(hv, uv, pv);
        tprev = tn;
    };

    // inclusive 8-lane segmented scan (3 masked row_shr stages)
    auto scan8 = [&](float x) -> float {
        float s1 = dpp_shr<0x111>(x); x += (u >= 1) ? s1 : 0.0f;
        float s2 = dpp_shr<0x112>(x); x += (u >= 2) ? s2 : 0.0f;
        float s4 = dpp_shr<0x114>(x); x += (u >= 4) ? s4 : 0.0f;
        return x;
    };

    int i = 1;
    int nch = N / CH;
    if (nch >= 4) {
        v2f raw0, raw1, raw2, raw3;    // .x = t[base+2u], .y = t[base+2u+1]
        int ngrp = nch / 4;
        int lim = N + 1 - CH;
        int u2 = 2*u;

        auto loadb = [&](v2f& b, int base) {
            b.x = trow[base + u2];
            b.y = trow[base + u2 + 1];
        };
        loadb(raw0, 1); loadb(raw1, 1 + CH); loadb(raw2, 1 + 2*CH);
        MEMBAR();

        for (int g = 0; g < ngrp; ++g) {
            int c = g * 4;
            // sub-block K: load chunk c+K+3; refresh; quadratic p-eval at the
            // lane's 2 own steps; EARLY carried-state update via red8 (VALU);
            // then scan + stores off the critical cycle.
#define SUB(BUFC, BUFL, K) do {                                             \
        int base = (c + (K) + 3)*CH + 1; if (base > lim) base = lim;        \
        loadb(BUFL, base);                                                  \
        MEMBAR();                                                           \
        refresh();                                                          \
        v2f uv  = vfma(splat(pv.y), C4v, vfma(splat(pv.x), C3v, C0v));      \
        v2f wv  = vfma(splat(uv.y), C4v, splat(uv.x) * C3v);                \
        v2f wh  = splat(0.5f) * wv;                                         \
        float tA = (BUFC).x, tB = (BUFC).y;                                 \
        float tPm = dpp_shr<0x111>(tB);                                     \
        float tP  = (u >= 1) ? tPm : tprev;                                 \
        float hA  = tA - tP, hB = tB - tA;                                  \
        float tauA = tP - tprev, tauB = tA - tprev;                         \
        v2f pA = vfma(splat(tauA), vfma(splat(tauA), wh, uv), pv);          \
        v2f pB = vfma(splat(tauB), vfma(splat(tauB), wh, uv), pv);          \
        v2f a  = splat(hA) * pA;                                            \
        v2f b  = splat(hB) * pB;                                            \
        v2f sv = a + b;                                                     \
        /* carried-state update first: the ONLY cross-chunk dependency */   \
        v2f CRbase = CRv;                                                   \
        v2f tot; tot.x = red8(sv.x); tot.y = red8(sv.y);                    \
        float hsum = red8(hA + hB);                                         \
        CRv = CRv + tot;                                                    \
        tprev = tprev + hsum;                                               \
        /* outputs: prefix scan + stores, off the carried cycle */          \
        v2f incl; incl.x = scan8(sv.x); incl.y = scan8(sv.y);               \
        v2f outB = CRbase + incl;                                           \
        v2f outA = outB - b;                                                \
        float2* sp = (float2*)orow + (size_t)((c + (K))*CH + 1);            \
        sp[u2]     = make_float2(outA.x, outA.y);                           \
        sp[u2 + 1] = make_float2(outB.x, outB.y);                           \
        MEMBAR();                                                           \
    } while (0)
            SUB(raw0, raw3, 0);
            SUB(raw1, raw0, 1);
            SUB(raw2, raw1, 2);
            SUB(raw3, raw2, 3);
#undef SUB
        }
        i = ngrp*4*CH + 1;
    }
    // tail (not hit for N=2048): refresh every step (exact), direct store
    for (; i <= N; ++i) {
        refresh();
        fstep(trow[i]);
        *(float2*)(orow + 2*(size_t)i) = make_float2(CRv.x, CRv.y);
    }
}

extern "C" void kernel_launch(void* const* d_in, const int* in_sizes, int n_in,
                              void* d_out, int out_size, void* d_ws, size_t ws_size,
                              hipStream_t stream) {
    const float* t  = (const float*)d_in[0];
    const float* Vs = (const float*)d_in[1];
    const float* Tm = (const float*)d_in[2];
    const float* C0 = (const float*)d_in[3];
    const float* R0 = (const float*)d_in[4];
    const float* W1 = (const float*)d_in[5];
    const float* b1 = (const float*)d_in[6];
    const float* W2 = (const float*)d_in[7];
    const float* b2 = (const float*)d_in[8];
    float* out = (float*)d_out;

    int B = in_sizes[1];
    int N = in_sizes[0] / B - 1;

    int threads = B * LPE;
    dim3 block(256);
    dim3 grid((threads + 255) / 256);
    hipLaunchKernelGGL(ode_scan, grid, block, 0, stream,
                       t, Vs, Tm, C0, R0, W1, b1, W2, b2, out, B, N);
}

// Round 21
// 38.754 us; speedup vs baseline: 1.2557x; 1.2557x over previous
//
#include <hip/hip_runtime.h>

// 8 lanes per batch element; 2 hidden units per lane packed as float2.
// Parallel chunk evaluation: refresh (exact exp2+rcp + DPP reduces) gives
// p0, C coefficients; each lane evaluates p(tau) at its 4 OWN steps by a
// CUBIC Taylor, forms weighted terms h*p, and chunk outputs come from one
// masked-DPP prefix scan + in-lane cumulative adds.
// R21: CH=32 (4 steps/lane) -- halves the chunk count (cross-chunk carried
// chains) and doubles prefetch slack in time; 4-buffer rotation kept.
#define LPE 8
#define CH 32   // steps per chunk == refresh period

typedef float v2f __attribute__((ext_vector_type(2)));

#if __has_builtin(__builtin_amdgcn_exp2f)
  #define EXP2F(x) __builtin_amdgcn_exp2f(x)
#else
  #define EXP2F(x) exp2f(x)
#endif
#if __has_builtin(__builtin_amdgcn_rcpf)
  #define RCPF(x) __builtin_amdgcn_rcpf(x)
#else
  #define RCPF(x) (1.0f/(x))
#endif

template<int CTRL>
__device__ __forceinline__ float dpp_add(float x) {
    int y = __builtin_amdgcn_update_dpp(0, __float_as_int(x), CTRL, 0xF, 0xF, true);
    return x + __int_as_float(y);
}
// butterfly sum over aligned 8-lane groups; all lanes get the total
__device__ __forceinline__ float red8(float v) {
    v = dpp_add<0xB1>(v);
    v = dpp_add<0x4E>(v);
    v = dpp_add<0x141>(v);
    return v;
}
// dpp row_shr:K with bound_ctrl (OOB -> 0)
template<int CTRL>
__device__ __forceinline__ float dpp_shr(float x) {
    int y = __builtin_amdgcn_update_dpp(0, __float_as_int(x), CTRL, 0xF, 0xF, true);
    return __int_as_float(y);
}

__device__ __forceinline__ v2f vfma(v2f a, v2f b, v2f c) {
#if __has_builtin(__builtin_elementwise_fma)
    return __builtin_elementwise_fma(a, b, c);
#else
    v2f r; r.x = fmaf(a.x, b.x, c.x); r.y = fmaf(a.y, b.y, c.y); return r;
#endif
}
__device__ __forceinline__ v2f splat(float x) { v2f v; v.x = x; v.y = x; return v; }

#define MEMBAR() __asm__ __volatile__("" ::: "memory")

struct TBuf { float t0, t1, t2, t3; };

__global__ __launch_bounds__(256, 1) void ode_scan(
    const float* __restrict__ t,
    const float* __restrict__ Vs,
    const float* __restrict__ Tm,
    const float* __restrict__ C0,
    const float* __restrict__ R0,
    const float* __restrict__ W1,   // (5,10)
    const float* __restrict__ b1,   // (10)
    const float* __restrict__ W2,   // (10,5)
    const float* __restrict__ b2,   // (5)
    float* __restrict__ out,        // (B, N+1, 2)
    int B, int N)
{
    int tid = blockIdx.x * blockDim.x + threadIdx.x;
    int e = tid >> 3;
    int u = tid & 7;
    if (e >= B) return;

    const float S   = 2.88539008177792681472f;   // 2*log2(e)
    const float LN2 = 0.69314718055994530942f;
    float Vv = Vs[e], Tv = Tm[e];

    // Packed per-lane weights for hidden units j0=2u (x), j1=2u+1 (y).
    v2f W0p, W3p, W4p, CCp, V3p, V4p;
    {
        int j0 = 2*u, j1 = 2*u + 1;
        if (j0 < 10) {
            W0p.x = S*W1[j0]; W3p.x = S*W1[30+j0]; W4p.x = S*W1[40+j0];
            CCp.x = S*fmaf(Vv, W1[10+j0], fmaf(Tv, W1[20+j0], b1[j0]));
            V3p.x = -2.0f*W2[5*j0+3]; V4p.x = -2.0f*W2[5*j0+4];
        } else { W0p.x=0.f; W3p.x=0.f; W4p.x=0.f; CCp.x=-60.f; V3p.x=0.f; V4p.x=0.f; }
        if (j1 < 10) {
            W0p.y = S*W1[j1]; W3p.y = S*W1[30+j1]; W4p.y = S*W1[40+j1];
            CCp.y = S*fmaf(Vv, W1[10+j1], fmaf(Tv, W1[20+j1], b1[j1]));
            V3p.y = -2.0f*W2[5*j1+3]; V4p.y = -2.0f*W2[5*j1+4];
        } else { W0p.y=0.f; W3p.y=0.f; W4p.y=0.f; CCp.y=-60.f; V3p.y=0.f; V4p.y=0.f; }
        if (j0 == 10) {
            // constant unit: a=-60 -> r==1.0 exactly, s==0 -> contributes the
            // exact constant to p3,p4 at refresh and ZERO to all C's.
            float c3 = b2[3], c4 = b2[4];
            for (int j = 0; j < 10; ++j) { c3 += W2[5*j+3]; c4 += W2[5*j+4]; }
            V3p.x = c3; V4p.x = c4;
        }
    }

    const v2f ONEv = splat(1.0f);
    v2f W0a = splat(LN2) * W0p, W3a = splat(LN2) * W3p, W4a = splat(LN2) * W4p;
    v2f M30 = W0a * V3p, M33 = W3a * V3p, M34 = W4a * V3p;
    v2f M40 = W0a * V4p, M43 = W3a * V4p, M44 = W4a * V4p;

    const float* trow = t + (size_t)e * (N + 1);
    float* orow = out + (size_t)e * (size_t)(N + 1) * 2;
    v2f CRv;                      // (Cap, Res) packed, group-uniform
    CRv.x = C0[e]; CRv.y = R0[e];
    *(float2*)orow = make_float2(CRv.x, CRv.y);
    float tprev = trow[0];        // group-uniform chunk-start t

    // group-uniform packed state
    v2f pv  = splat(0.0f);                      // (p3, p4)
    v2f C0v = splat(0.0f), C3v = splat(0.0f), C4v = splat(0.0f);

    // refresh: exact per-unit r from (tprev, CRv), reduce p0 and the six C's.
    auto refresh = [&]() {
        v2f TP = vfma(splat(tprev), W0p, CCp);
        v2f A  = vfma(splat(CRv.y), W4p, vfma(splat(CRv.x), W3p, TP));
        v2f zz; zz.x = EXP2F(A.x); zz.y = EXP2F(A.y);
        v2f dd = zz + ONEv;
        v2f rr; rr.x = RCPF(dd.x); rr.y = RCPF(dd.y);
        v2f ss = vfma(rr, rr, -rr);      // s = r^2 - r
        v2f l3 = rr * V3p, l4 = rr * V4p;
        v2f k30 = ss * M30, k33 = ss * M33, k34 = ss * M34;
        v2f k40 = ss * M40, k43 = ss * M43, k44 = ss * M44;
        pv.x  = red8(l3.x + l3.y);
        pv.y  = red8(l4.x + l4.y);
        C0v.x = red8(k30.x + k30.y);
        C3v.x = red8(k33.x + k33.y);
        C4v.x = red8(k34.x + k34.y);
        C0v.y = red8(k40.x + k40.y);
        C3v.y = red8(k43.x + k43.y);
        C4v.y = red8(k44.x + k44.y);
    };

    // sequential exact step (tail only)
    auto fstep = [&](float tn) {
        float h  = tn - tprev;
        v2f hv   = splat(h);
        v2f uv   = vfma(splat(pv.y), C4v, vfma(splat(pv.x), C3v, C0v));
        CRv = vfma(hv, pv, CRv);
        pv  = vfma(hv, uv, pv);
        tprev = tn;
    };

    // inclusive 8-lane segmented scan (3 masked row_shr stages)
    auto scan8 = [&](float x) -> float {
        float s1 = dpp_shr<0x111>(x); x += (u >= 1) ? s1 : 0.0f;
        float s2 = dpp_shr<0x112>(x); x += (u >= 2) ? s2 : 0.0f;
        float s4 = dpp_shr<0x114>(x); x += (u >= 4) ? s4 : 0.0f;
        return x;
    };

    int i = 1;
    int nch = N / CH;
    if (nch >= 4) {
        TBuf raw0, raw1, raw2, raw3;   // lane u holds t[base+4u .. base+4u+3]
        int ngrp = nch / 4;
        int lim = N + 1 - CH;
        int u4 = 4*u;

        auto loadb = [&](TBuf& b, int base) {
            b.t0 = trow[base + u4];
            b.t1 = trow[base + u4 + 1];
            b.t2 = trow[base + u4 + 2];
            b.t3 = trow[base + u4 + 3];
        };
        loadb(raw0, 1); loadb(raw1, 1 + CH); loadb(raw2, 1 + 2*CH);
        MEMBAR();

        for (int g = 0; g < ngrp; ++g) {
            int c = g * 4;
            // sub-block K: load chunk c+K+3; refresh; cubic p-eval at the
            // lane's 4 own steps; early carried-state update via red8;
            // prefix scan + in-lane cumulative outputs + 4 float2 stores.
#define SUB(BUFC, BUFL, K) do {                                             \
        int base = (c + (K) + 3)*CH + 1; if (base > lim) base = lim;        \
        loadb(BUFL, base);                                                  \
        MEMBAR();                                                           \
        refresh();                                                          \
        v2f uv  = vfma(splat(pv.y), C4v, vfma(splat(pv.x), C3v, C0v));      \
        v2f wv  = vfma(splat(uv.y), C4v, splat(uv.x) * C3v);                \
        v2f xv  = vfma(splat(wv.y), C4v, splat(wv.x) * C3v);                \
        v2f wh  = splat(0.5f) * wv;                                         \
        v2f xh  = splat(0.16666667f) * xv;                                  \
        float tc0 = (BUFC).t0, tc1 = (BUFC).t1;                             \
        float tc2 = (BUFC).t2, tc3 = (BUFC).t3;                             \
        float tPm = dpp_shr<0x111>(tc3);                                    \
        float tP  = (u >= 1) ? tPm : tprev;                                 \
        float h0 = tc0 - tP,  h1 = tc1 - tc0;                               \
        float h2 = tc2 - tc1, h3 = tc3 - tc2;                               \
        float ta0 = tP  - tprev, ta1 = tc0 - tprev;                         \
        float ta2 = tc1 - tprev, ta3 = tc2 - tprev;                         \
        v2f p0 = vfma(splat(ta0), vfma(splat(ta0), vfma(splat(ta0), xh, wh), uv), pv); \
        v2f p1 = vfma(splat(ta1), vfma(splat(ta1), vfma(splat(ta1), xh, wh), uv), pv); \
        v2f p2 = vfma(splat(ta2), vfma(splat(ta2), vfma(splat(ta2), xh, wh), uv), pv); \
        v2f p3t = vfma(splat(ta3), vfma(splat(ta3), vfma(splat(ta3), xh, wh), uv), pv); \
        v2f a0 = splat(h0) * p0, a1 = splat(h1) * p1;                       \
        v2f a2 = splat(h2) * p2, a3 = splat(h3) * p3t;                      \
        v2f sv = (a0 + a1) + (a2 + a3);                                     \
        /* carried-state update first: the ONLY cross-chunk dependency */   \
        v2f CRbase = CRv;                                                   \
        v2f tot; tot.x = red8(sv.x); tot.y = red8(sv.y);                    \
        float hsum = red8(tc3 - tP);                                        \
        CRv = CRv + tot;                                                    \
        tprev = tprev + hsum;                                               \
        /* outputs: prefix scan + cumulative stores, off the carried cycle */\
        v2f incl; incl.x = scan8(sv.x); incl.y = scan8(sv.y);               \
        v2f o0 = (CRbase + (incl - sv)) + a0;                               \
        v2f o1 = o0 + a1;                                                   \
        v2f o2 = o1 + a2;                                                   \
        v2f o3 = o2 + a3;                                                   \
        float2* sp = (float2*)orow + (size_t)((c + (K))*CH + 1);            \
        sp[u4]     = make_float2(o0.x, o0.y);                               \
        sp[u4 + 1] = make_float2(o1.x, o1.y);                               \
        sp[u4 + 2] = make_float2(o2.x, o2.y);                               \
        sp[u4 + 3] = make_float2(o3.x, o3.y);                               \
        MEMBAR();                                                           \
    } while (0)
            SUB(raw0, raw3, 0);
            SUB(raw1, raw0, 1);
            SUB(raw2, raw1, 2);
            SUB(raw3, raw2, 3);
#undef SUB
        }
        i = ngrp*4*CH + 1;
    }
    // tail (not hit for N=2048): refresh every step (exact), direct store
    for (; i <= N; ++i) {
        refresh();
        fstep(trow[i]);
        *(float2*)(orow + 2*(size_t)i) = make_float2(CRv.x, CRv.y);
    }
}

extern "C" void kernel_launch(void* const* d_in, const int* in_sizes, int n_in,
                              void* d_out, int out_size, void* d_ws, size_t ws_size,
                              hipStream_t stream) {
    const float* t  = (const float*)d_in[0];
    const float* Vs = (const float*)d_in[1];
    const float* Tm = (const float*)d_in[2];
    const float* C0 = (const float*)d_in[3];
    const float* R0 = (const float*)d_in[4];
    const float* W1 = (const float*)d_in[5];
    const float* b1 = (const float*)d_in[6];
    const float* W2 = (const float*)d_in[7];
    const float* b2 = (const float*)d_in[8];
    float* out = (float*)d_out;

    int B = in_sizes[1];
    int N = in_sizes[0] / B - 1;

    int threads = B * LPE;
    dim3 block(256);
    dim3 grid((threads + 255) / 256);
    hipLaunchKernelGGL(ode_scan, grid, block, 0, stream,
                       t, Vs, Tm, C0, R0, W1, b1, W2, b2, out, B, N);
}

// Round 22
// 38.624 us; speedup vs baseline: 1.2599x; 1.0034x over previous
//
#include <hip/hip_runtime.h>

// 8 lanes per batch element; 2 hidden units per lane packed as float2.
// Parallel chunk evaluation (R21): refresh -> cubic Taylor p(tau) at the
// lane's 4 own steps -> masked-DPP prefix scan + in-lane cumulative outputs.
// R22: vectorized VMEM. Lane's 4 t-loads = one dwordx4 (16B, dword-aligned);
// lane's 4 float2 outputs = two dwordx4 stores (32B contiguous). 8 VMEM
// instrs/SUB -> 3. Math bit-identical to R21.
#define LPE 8
#define CH 32   // steps per chunk == refresh period

typedef float v2f __attribute__((ext_vector_type(2)));

#if __has_builtin(__builtin_amdgcn_exp2f)
  #define EXP2F(x) __builtin_amdgcn_exp2f(x)
#else
  #define EXP2F(x) exp2f(x)
#endif
#if __has_builtin(__builtin_amdgcn_rcpf)
  #define RCPF(x) __builtin_amdgcn_rcpf(x)
#else
  #define RCPF(x) (1.0f/(x))
#endif

template<int CTRL>
__device__ __forceinline__ float dpp_add(float x) {
    int y = __builtin_amdgcn_update_dpp(0, __float_as_int(x), CTRL, 0xF, 0xF, true);
    return x + __int_as_float(y);
}
// butterfly sum over aligned 8-lane groups; all lanes get the total
__device__ __forceinline__ float red8(float v) {
    v = dpp_add<0xB1>(v);
    v = dpp_add<0x4E>(v);
    v = dpp_add<0x141>(v);
    return v;
}
// dpp row_shr:K with bound_ctrl (OOB -> 0)
template<int CTRL>
__device__ __forceinline__ float dpp_shr(float x) {
    int y = __builtin_amdgcn_update_dpp(0, __float_as_int(x), CTRL, 0xF, 0xF, true);
    return __int_as_float(y);
}

__device__ __forceinline__ v2f vfma(v2f a, v2f b, v2f c) {
#if __has_builtin(__builtin_elementwise_fma)
    return __builtin_elementwise_fma(a, b, c);
#else
    v2f r; r.x = fmaf(a.x, b.x, c.x); r.y = fmaf(a.y, b.y, c.y); return r;
#endif
}
__device__ __forceinline__ v2f splat(float x) { v2f v; v.x = x; v.y = x; return v; }

#define MEMBAR() __asm__ __volatile__("" ::: "memory")

struct TBuf { float t0, t1, t2, t3; };

// 16B load/store at dword alignment (backend emits global_*_dwordx4)
__device__ __forceinline__ void load16(TBuf& b, const float* p) {
    float4 v;
    __builtin_memcpy(&v, p, 16);
    b.t0 = v.x; b.t1 = v.y; b.t2 = v.z; b.t3 = v.w;
}
__device__ __forceinline__ void store16(float* p, float a, float b_, float c, float d) {
    float4 v = make_float4(a, b_, c, d);
    __builtin_memcpy(p, &v, 16);
}

__global__ __launch_bounds__(256, 1) void ode_scan(
    const float* __restrict__ t,
    const float* __restrict__ Vs,
    const float* __restrict__ Tm,
    const float* __restrict__ C0,
    const float* __restrict__ R0,
    const float* __restrict__ W1,   // (5,10)
    const float* __restrict__ b1,   // (10)
    const float* __restrict__ W2,   // (10,5)
    const float* __restrict__ b2,   // (5)
    float* __restrict__ out,        // (B, N+1, 2)
    int B, int N)
{
    int tid = blockIdx.x * blockDim.x + threadIdx.x;
    int e = tid >> 3;
    int u = tid & 7;
    if (e >= B) return;

    const float S   = 2.88539008177792681472f;   // 2*log2(e)
    const float LN2 = 0.69314718055994530942f;
    float Vv = Vs[e], Tv = Tm[e];

    // Packed per-lane weights for hidden units j0=2u (x), j1=2u+1 (y).
    v2f W0p, W3p, W4p, CCp, V3p, V4p;
    {
        int j0 = 2*u, j1 = 2*u + 1;
        if (j0 < 10) {
            W0p.x = S*W1[j0]; W3p.x = S*W1[30+j0]; W4p.x = S*W1[40+j0];
            CCp.x = S*fmaf(Vv, W1[10+j0], fmaf(Tv, W1[20+j0], b1[j0]));
            V3p.x = -2.0f*W2[5*j0+3]; V4p.x = -2.0f*W2[5*j0+4];
        } else { W0p.x=0.f; W3p.x=0.f; W4p.x=0.f; CCp.x=-60.f; V3p.x=0.f; V4p.x=0.f; }
        if (j1 < 10) {
            W0p.y = S*W1[j1]; W3p.y = S*W1[30+j1]; W4p.y = S*W1[40+j1];
            CCp.y = S*fmaf(Vv, W1[10+j1], fmaf(Tv, W1[20+j1], b1[j1]));
            V3p.y = -2.0f*W2[5*j1+3]; V4p.y = -2.0f*W2[5*j1+4];
        } else { W0p.y=0.f; W3p.y=0.f; W4p.y=0.f; CCp.y=-60.f; V3p.y=0.f; V4p.y=0.f; }
        if (j0 == 10) {
            // constant unit: a=-60 -> r==1.0 exactly, s==0 -> contributes the
            // exact constant to p3,p4 at refresh and ZERO to all C's.
            float c3 = b2[3], c4 = b2[4];
            for (int j = 0; j < 10; ++j) { c3 += W2[5*j+3]; c4 += W2[5*j+4]; }
            V3p.x = c3; V4p.x = c4;
        }
    }

    const v2f ONEv = splat(1.0f);
    v2f W0a = splat(LN2) * W0p, W3a = splat(LN2) * W3p, W4a = splat(LN2) * W4p;
    v2f M30 = W0a * V3p, M33 = W3a * V3p, M34 = W4a * V3p;
    v2f M40 = W0a * V4p, M43 = W3a * V4p, M44 = W4a * V4p;

    const float* trow = t + (size_t)e * (N + 1);
    float* orow = out + (size_t)e * (size_t)(N + 1) * 2;
    v2f CRv;                      // (Cap, Res) packed, group-uniform
    CRv.x = C0[e]; CRv.y = R0[e];
    *(float2*)orow = make_float2(CRv.x, CRv.y);
    float tprev = trow[0];        // group-uniform chunk-start t

    // group-uniform packed state
    v2f pv  = splat(0.0f);                      // (p3, p4)
    v2f C0v = splat(0.0f), C3v = splat(0.0f), C4v = splat(0.0f);

    // refresh: exact per-unit r from (tprev, CRv), reduce p0 and the six C's.
    auto refresh = [&]() {
        v2f TP = vfma(splat(tprev), W0p, CCp);
        v2f A  = vfma(splat(CRv.y), W4p, vfma(splat(CRv.x), W3p, TP));
        v2f zz; zz.x = EXP2F(A.x); zz.y = EXP2F(A.y);
        v2f dd = zz + ONEv;
        v2f rr; rr.x = RCPF(dd.x); rr.y = RCPF(dd.y);
        v2f ss = vfma(rr, rr, -rr);      // s = r^2 - r
        v2f l3 = rr * V3p, l4 = rr * V4p;
        v2f k30 = ss * M30, k33 = ss * M33, k34 = ss * M34;
        v2f k40 = ss * M40, k43 = ss * M43, k44 = ss * M44;
        pv.x  = red8(l3.x + l3.y);
        pv.y  = red8(l4.x + l4.y);
        C0v.x = red8(k30.x + k30.y);
        C3v.x = red8(k33.x + k33.y);
        C4v.x = red8(k34.x + k34.y);
        C0v.y = red8(k40.x + k40.y);
        C3v.y = red8(k43.x + k43.y);
        C4v.y = red8(k44.x + k44.y);
    };

    // sequential exact step (tail only)
    auto fstep = [&](float tn) {
        float h  = tn - tprev;
        v2f hv   = splat(h);
        v2f uv   = vfma(splat(pv.y), C4v, vfma(splat(pv.x), C3v, C0v));
        CRv = vfma(hv, pv, CRv);
        pv  = vfma(hv, uv, pv);
        tprev = tn;
    };

    // inclusive 8-lane segmented scan (3 masked row_shr stages)
    auto scan8 = [&](float x) -> float {
        float s1 = dpp_shr<0x111>(x); x += (u >= 1) ? s1 : 0.0f;
        float s2 = dpp_shr<0x112>(x); x += (u >= 2) ? s2 : 0.0f;
        float s4 = dpp_shr<0x114>(x); x += (u >= 4) ? s4 : 0.0f;
        return x;
    };

    int i = 1;
    int nch = N / CH;
    if (nch >= 4) {
        TBuf raw0, raw1, raw2, raw3;   // lane u holds t[base+4u .. base+4u+3]
        int ngrp = nch / 4;
        int lim = N + 1 - CH;
        int u4 = 4*u;

        load16(raw0, trow + 1 + u4);
        load16(raw1, trow + 1 + CH + u4);
        load16(raw2, trow + 1 + 2*CH + u4);
        MEMBAR();

        for (int g = 0; g < ngrp; ++g) {
            int c = g * 4;
            // sub-block K: load chunk c+K+3; refresh; cubic p-eval at the
            // lane's 4 own steps; early carried-state update via red8;
            // prefix scan + in-lane cumulative outputs + 2 dwordx4 stores.
#define SUB(BUFC, BUFL, K) do {                                             \
        int base = (c + (K) + 3)*CH + 1; if (base > lim) base = lim;        \
        load16(BUFL, trow + base + u4);                                     \
        MEMBAR();                                                           \
        refresh();                                                          \
        v2f uv  = vfma(splat(pv.y), C4v, vfma(splat(pv.x), C3v, C0v));      \
        v2f wv  = vfma(splat(uv.y), C4v, splat(uv.x) * C3v);                \
        v2f xv  = vfma(splat(wv.y), C4v, splat(wv.x) * C3v);                \
        v2f wh  = splat(0.5f) * wv;                                         \
        v2f xh  = splat(0.16666667f) * xv;                                  \
        float tc0 = (BUFC).t0, tc1 = (BUFC).t1;                             \
        float tc2 = (BUFC).t2, tc3 = (BUFC).t3;                             \
        float tPm = dpp_shr<0x111>(tc3);                                    \
        float tP  = (u >= 1) ? tPm : tprev;                                 \
        float h0 = tc0 - tP,  h1 = tc1 - tc0;                               \
        float h2 = tc2 - tc1, h3 = tc3 - tc2;                               \
        float ta0 = tP  - tprev, ta1 = tc0 - tprev;                         \
        float ta2 = tc1 - tprev, ta3 = tc2 - tprev;                         \
        v2f p0 = vfma(splat(ta0), vfma(splat(ta0), vfma(splat(ta0), xh, wh), uv), pv); \
        v2f p1 = vfma(splat(ta1), vfma(splat(ta1), vfma(splat(ta1), xh, wh), uv), pv); \
        v2f p2 = vfma(splat(ta2), vfma(splat(ta2), vfma(splat(ta2), xh, wh), uv), pv); \
        v2f p3t = vfma(splat(ta3), vfma(splat(ta3), vfma(splat(ta3), xh, wh), uv), pv); \
        v2f a0 = splat(h0) * p0, a1 = splat(h1) * p1;                       \
        v2f a2 = splat(h2) * p2, a3 = splat(h3) * p3t;                      \
        v2f sv = (a0 + a1) + (a2 + a3);                                     \
        /* carried-state update first: the ONLY cross-chunk dependency */   \
        v2f CRbase = CRv;                                                   \
        v2f tot; tot.x = red8(sv.x); tot.y = red8(sv.y);                    \
        float hsum = red8(tc3 - tP);                                        \
        CRv = CRv + tot;                                                    \
        tprev = tprev + hsum;                                               \
        /* outputs: prefix scan + cumulative stores, off the carried cycle */\
        v2f incl; incl.x = scan8(sv.x); incl.y = scan8(sv.y);               \
        v2f o0 = (CRbase + (incl - sv)) + a0;                               \
        v2f o1 = o0 + a1;                                                   \
        v2f o2 = o1 + a2;                                                   \
        v2f o3 = o2 + a3;                                                   \
        float* sp = orow + 2*(size_t)((c + (K))*CH + 1 + u4);               \
        store16(sp,     o0.x, o0.y, o1.x, o1.y);                            \
        store16(sp + 4, o2.x, o2.y, o3.x, o3.y);                            \
        MEMBAR();                                                           \
    } while (0)
            SUB(raw0, raw3, 0);
            SUB(raw1, raw0, 1);
            SUB(raw2, raw1, 2);
            SUB(raw3, raw2, 3);
#undef SUB
        }
        i = ngrp*4*CH + 1;
    }
    // tail (not hit for N=2048): refresh every step (exact), direct store
    for (; i <= N; ++i) {
        refresh();
        fstep(trow[i]);
        *(float2*)(orow + 2*(size_t)i) = make_float2(CRv.x, CRv.y);
    }
}

extern "C" void kernel_launch(void* const* d_in, const int* in_sizes, int n_in,
                              void* d_out, int out_size, void* d_ws, size_t ws_size,
                              hipStream_t stream) {
    const float* t  = (const float*)d_in[0];
    const float* Vs = (const float*)d_in[1];
    const float* Tm = (const float*)d_in[2];
    const float* C0 = (const float*)d_in[3];
    const float* R0 = (const float*)d_in[4];
    const float* W1 = (const float*)d_in[5];
    const float* b1 = (const float*)d_in[6];
    const float* W2 = (const float*)d_in[7];
    const float* b2 = (const float*)d_in[8];
    float* out = (float*)d_out;

    int B = in_sizes[1];
    int N = in_sizes[0] / B - 1;

    int threads = B * LPE;
    dim3 block(256);
    dim3 grid((threads + 255) / 256);
    hipLaunchKernelGGL(ode_scan, grid, block, 0, stream,
                       t, Vs, Tm, C0, R0, W1, b1, W2, b2, out, B, N);
}